// Round 16
// baseline (443.147 us; speedup 1.0000x reference)
//
#include <hip/hip_runtime.h>
#include <hip/hip_bf16.h>

#define HH 32
#define WW 32
#define CC 256
#define OO 512
#define BB 64
#define HWC (HH*WW*CC)
#define HWO (HH*WW*OO)
#define EPS 1e-3f
#define ALPHA 0.2f

typedef __attribute__((ext_vector_type(8))) short short8;
typedef __attribute__((ext_vector_type(4))) float f32x4;
typedef __attribute__((ext_vector_type(2))) float float2v;
typedef __attribute__((ext_vector_type(4))) unsigned uint4_;

__device__ __forceinline__ short f2bf(float f) {
    return (short)__builtin_bit_cast(unsigned short, __float2bfloat16(f));
}

// ---- kernel 0: transpose taps (3,3,C,O) f32 -> (t,O,C) bf16 in ws ----
__global__ __launch_bounds__(256) void transpose_taps(const float* __restrict__ w,
                                                      short* __restrict__ tt) {
    __shared__ float tile[64][65];
    const int bid = blockIdx.x;
    const int t  = bid >> 5;          // 0..8
    const int ct = (bid >> 3) & 3;    // c tile
    const int ob = bid & 7;           // o tile
    const int c0 = ct * 64, o0 = ob * 64;
    const int tid = threadIdx.x;
    const int col = tid & 63;
    const int rq  = tid >> 6;         // 0..3
    #pragma unroll
    for (int r = 0; r < 16; ++r) {
        int c_loc = r * 4 + rq;
        tile[c_loc][col] = w[(size_t)(t * CC + c0 + c_loc) * OO + o0 + col];
    }
    __syncthreads();
    #pragma unroll
    for (int r = 0; r < 16; ++r) {
        int o_loc = r * 4 + rq;
        tt[(size_t)(t * OO + o0 + o_loc) * CC + c0 + col] = f2bf(tile[col][o_loc]);
    }
}

// ---- main fused kernel: 4096 blocks x 512 thr; 128-o tile, n=1 per wave ----
// r10 structure + x-load hoist (T14, 16-reg hold): x loads for chunk ch+1
// issue right after sx(ch) is written; their latency hides under construct.
__global__ __launch_bounds__(512, 4) void cdot_mfma(
    const float* __restrict__ xr, const float* __restrict__ xi,
    const short* __restrict__ taps,     // (t, o, c) bf16
    const float* __restrict__ gr, const float* __restrict__ br,
    const float* __restrict__ mr, const float* __restrict__ vr,
    const float* __restrict__ gi, const float* __restrict__ bi,
    const float* __restrict__ mi_, const float* __restrict__ vi,
    float* __restrict__ outr, float* __restrict__ outi)
{
    // sx: [2 ri][64 b][64 c] bf16, XOR-swizzled in 8-elt groups. 16 KB.
    // sw: w_freq chunk, R plane [128 o][64 c] + I plane, same swizzle. 32 KB.
    __shared__ short sx[8192];
    __shared__ short sw[16384];

    const int tid  = threadIdx.x;
    const int lane = tid & 63;
    const int wave = tid >> 6;        // 0..7
    const int laneO = lane & 15;
    const int laneW = lane >> 4;

    // uv-major XCD remap (r10 form): 4 same-uv blocks on one XCD's L2.
    const int p   = blockIdx.x;
    const int xcd = p & 7;
    const int r_  = p >> 3;            // 0..511
    const int uv  = xcd * 128 + (r_ >> 2);
    const int ot  = r_ & 3;            // o-tile of 128
    const int u = uv >> 5, v = uv & 31;
    const int o0 = ot * 128;
    const int owave = o0 + wave * 16;  // 16 o per wave (n=1)

    // twiddles e^{-2pi i (u p + v q)/32} (sin pre-negated)
    float cs[9], sn[9];
    #pragma unroll
    for (int pp = 0; pp < 3; ++pp) {
        #pragma unroll
        for (int qq = 0; qq < 3; ++qq) {
            int k = (u*pp + v*qq) & 31;
            float a = (float)k * 0.0625f;
            cs[pp*3+qq] = cospif(a);
            sn[pp*3+qq] = -sinpif(a);
        }
    }

    f32x4 accR[4], accI[4];
    #pragma unroll
    for (int m = 0; m < 4; ++m) { accR[m] = (f32x4)(0.0f); accI[m] = (f32x4)(0.0f); }

    // construct assignment: 8 lanes per o-row -> 128 B contiguous tap runs
    const int c8w = (tid & 7) * 8;         // chunk-local c octet base
    const int orw = tid >> 3;              // o-row 0..63 (+64 on pass 1)

    // stage slots (fixed per thread)
    const float* ssrc[2];
    int sidx[2];
    #pragma unroll
    for (int it = 0; it < 2; ++it) {
        int s  = tid + it * 512;           // 0..1023
        int ri = s >> 9;
        int rr = s & 511;
        int b  = rr >> 3;
        int c8 = (rr & 7) * 8;
        ssrc[it] = (ri ? xi : xr) + (size_t)b * HWC + uv * CC + c8;
        sidx[it] = ri * 4096 + b * 64 + (c8 ^ ((b & 7) * 8));
    }

    float4 xf[4];
    auto load_xf = [&](int kc0) {
        #pragma unroll
        for (int it = 0; it < 2; ++it) {
            xf[2*it]   = *(const float4*)(ssrc[it] + kc0);
            xf[2*it+1] = *(const float4*)(ssrc[it] + kc0 + 4);
        }
    };
    auto write_xf = [&]() {
        #pragma unroll
        for (int it = 0; it < 2; ++it) {
            float4 f0 = xf[2*it], f1 = xf[2*it+1];
            short8 pk;
            pk[0]=f2bf(f0.x); pk[1]=f2bf(f0.y); pk[2]=f2bf(f0.z); pk[3]=f2bf(f0.w);
            pk[4]=f2bf(f1.x); pk[5]=f2bf(f1.y); pk[6]=f2bf(f1.z); pk[7]=f2bf(f1.w);
            *(short8*)(sx + sidx[it]) = pk;
        }
    };

    // ---- prologue: issue chunk-0 x loads ----
    load_xf(0);

    #pragma unroll
    for (int ch = 0; ch < 4; ++ch) {
        const int kc0 = ch * 64;
        __syncthreads();               // previous MFMA reads done; LDS reusable

        // ---- write prefetched x to sx (data already in flight/arrived) ----
        write_xf();
        // ---- issue next chunk's x loads: latency hides under construct ----
        if (ch < 3) load_xf(kc0 + 64);

        // ---- construct w_freq chunk into LDS (r10 form) ----
        #pragma unroll
        for (int pass = 0; pass < 2; ++pass) {
            const int ol = orw + pass * 64;        // local o 0..127
            const short* tb = taps + (size_t)(o0 + ol) * CC + kc0 + c8w;
            float2v ar[4], ai[4];
            #pragma unroll
            for (int j = 0; j < 4; ++j) { ar[j] = (float2v)(0.0f); ai[j] = (float2v)(0.0f); }
            #pragma unroll
            for (int t = 0; t < 9; ++t) {
                short8 tp = *(const short8*)(tb + (size_t)t * (OO * CC));
                uint4_ tu = __builtin_bit_cast(uint4_, tp);
                float2v cst = (float2v)(cs[t]);
                float2v snt = (float2v)(sn[t]);
                #pragma unroll
                for (int j = 0; j < 4; ++j) {
                    unsigned uw = tu[j];
                    float2v f;
                    f.x = __uint_as_float(uw << 16);
                    f.y = __uint_as_float(uw & 0xffff0000u);
                    ar[j] = __builtin_elementwise_fma(cst, f, ar[j]);
                    ai[j] = __builtin_elementwise_fma(snt, f, ai[j]);
                }
            }
            short8 pR, pI;
            #pragma unroll
            for (int j = 0; j < 4; ++j) {
                pR[2*j]   = f2bf(ar[j].x);
                pR[2*j+1] = f2bf(ar[j].y);
                pI[2*j]   = f2bf(ai[j].x);
                pI[2*j+1] = f2bf(ai[j].y);
            }
            int widx = ol * 64 + (c8w ^ ((ol & 7) * 8));
            *(short8*)(sw + widx)        = pR;
            *(short8*)(sw + 8192 + widx) = pI;
        }
        __syncthreads();

        // ---- MFMA sweep: pure LDS + MFMA (r10 form) ----
        #pragma unroll
        for (int ks = 0; ks < 2; ++ks) {
            const int ol  = wave * 16 + laneO;     // local o 0..127
            const int cpr = (ks * 32 + laneW * 8) ^ ((ol & 7) * 8);
            short8 bR = *(const short8*)(sw + ol * 64 + cpr);
            short8 bI = *(const short8*)(sw + 8192 + ol * 64 + cpr);
            uint4_ bu = __builtin_bit_cast(uint4_, bR);
            bu ^= 0x80008000u;                     // -wr for imag part
            short8 bRn = __builtin_bit_cast(short8, bu);

            const int cidx = (ks * 32 + laneW * 8) ^ ((laneO & 7) * 8);
            __builtin_amdgcn_s_setprio(1);
            #pragma unroll
            for (int m = 0; m < 4; ++m) {
                int b = m * 16 + laneO;
                short8 a0 = *(const short8*)(sx + b * 64 + cidx);
                short8 a1 = *(const short8*)(sx + 4096 + b * 64 + cidx);
                accR[m] = __builtin_amdgcn_mfma_f32_16x16x32_bf16(a0, bR,  accR[m], 0, 0, 0);
                accR[m] = __builtin_amdgcn_mfma_f32_16x16x32_bf16(a1, bI,  accR[m], 0, 0, 0);
                accI[m] = __builtin_amdgcn_mfma_f32_16x16x32_bf16(a0, bI,  accI[m], 0, 0, 0);
                accI[m] = __builtin_amdgcn_mfma_f32_16x16x32_bf16(a1, bRn, accI[m], 0, 0, 0);
            }
            __builtin_amdgcn_s_setprio(0);
        }
    }

    // ---- epilogue: BN + LeakyReLU, coalesced stores ----
    {
        const int o = owave + laneO;
        float scR = gr[o] * rsqrtf(vr[o] + EPS);
        float mR = mr[o], bR_ = br[o];
        float scI = gi[o] * rsqrtf(vi[o] + EPS);
        float mI = mi_[o], bI_ = bi[o];
        #pragma unroll
        for (int m = 0; m < 4; ++m) {
            #pragma unroll
            for (int e = 0; e < 4; ++e) {
                int b = m * 16 + laneW * 4 + e;
                size_t idx = (size_t)b * HWO + (size_t)uv * OO + o;
                float yr = (accR[m][e] - mR) * scR + bR_;
                outr[idx] = (yr >= 0.f) ? yr : ALPHA * yr;
                float yi = (accI[m][e] - mI) * scI + bI_;
                outi[idx] = (yi >= 0.f) ? yi : ALPHA * yi;
            }
        }
    }
}

extern "C" void kernel_launch(void* const* d_in, const int* in_sizes, int n_in,
                              void* d_out, int out_size, void* d_ws, size_t ws_size,
                              hipStream_t stream) {
    const float* xr = (const float*)d_in[0];
    const float* xi = (const float*)d_in[1];
    const float* w  = (const float*)d_in[2];
    const float* gr = (const float*)d_in[3];
    const float* br = (const float*)d_in[4];
    const float* mr = (const float*)d_in[5];
    const float* vr = (const float*)d_in[6];
    const float* gi = (const float*)d_in[7];
    const float* bi = (const float*)d_in[8];
    const float* mi_ = (const float*)d_in[9];
    const float* vi = (const float*)d_in[10];

    short* taps_t = (short*)d_ws;               // 9*512*256 bf16 = 2.36 MB
    float* outr = (float*)d_out;
    float* outi = outr + (size_t)BB * HWO;

    transpose_taps<<<288, 256, 0, stream>>>(w, taps_t);
    cdot_mfma<<<4096, 512, 0, stream>>>(xr, xi, taps_t,
                                        gr, br, mr, vr,
                                        gi, bi, mi_, vi,
                                        outr, outi);
}

// Round 17
// 350.755 us; speedup vs baseline: 1.2634x; 1.2634x over previous
//
#include <hip/hip_runtime.h>
#include <hip/hip_bf16.h>

#define HH 32
#define WW 32
#define CC 256
#define OO 512
#define BB 64
#define HWC (HH*WW*CC)
#define HWO (HH*WW*OO)
#define EPS 1e-3f
#define ALPHA 0.2f

typedef __attribute__((ext_vector_type(8))) short short8;
typedef __attribute__((ext_vector_type(4))) float f32x4;
typedef __attribute__((ext_vector_type(2))) float float2v;
typedef __attribute__((ext_vector_type(4))) unsigned uint4_;

__device__ __forceinline__ short f2bf(float f) {
    return (short)__builtin_bit_cast(unsigned short, __float2bfloat16(f));
}

// ---- kernel 0: transpose taps (3,3,C,O) f32 -> (t,O,C) bf16 in ws ----
__global__ __launch_bounds__(256) void transpose_taps(const float* __restrict__ w,
                                                      short* __restrict__ tt) {
    __shared__ float tile[64][65];
    const int bid = blockIdx.x;
    const int t  = bid >> 5;          // 0..8
    const int ct = (bid >> 3) & 3;    // c tile
    const int ob = bid & 7;           // o tile
    const int c0 = ct * 64, o0 = ob * 64;
    const int tid = threadIdx.x;
    const int col = tid & 63;
    const int rq  = tid >> 6;         // 0..3
    #pragma unroll
    for (int r = 0; r < 16; ++r) {
        int c_loc = r * 4 + rq;
        tile[c_loc][col] = w[(size_t)(t * CC + c0 + c_loc) * OO + o0 + col];
    }
    __syncthreads();
    #pragma unroll
    for (int r = 0; r < 16; ++r) {
        int o_loc = r * 4 + rq;
        tt[(size_t)(t * OO + o0 + o_loc) * CC + c0 + col] = f2bf(tile[col][o_loc]);
    }
}

// ---- main fused kernel: 4096 blocks x 512 thr; 128-o tile, n=1 per wave ----
// B fragments constructed IN REGISTERS (no sw LDS); sx double-buffered with
// ONE barrier per chunk.
__global__ __launch_bounds__(512, 4) void cdot_mfma(
    const float* __restrict__ xr, const float* __restrict__ xi,
    const short* __restrict__ taps,     // (t, o, c) bf16
    const float* __restrict__ gr, const float* __restrict__ br,
    const float* __restrict__ mr, const float* __restrict__ vr,
    const float* __restrict__ gi, const float* __restrict__ bi,
    const float* __restrict__ mi_, const float* __restrict__ vi,
    float* __restrict__ outr, float* __restrict__ outi)
{
    // sx: 2 x [2 ri][64 b][64 c] bf16, XOR-swizzled in 8-elt groups. 32 KB.
    __shared__ short sx[2 * 8192];

    const int tid  = threadIdx.x;
    const int lane = tid & 63;
    const int wave = tid >> 6;        // 0..7
    const int laneO = lane & 15;
    const int laneW = lane >> 4;

    // uv-major XCD remap (r10 form): 4 same-uv blocks on one XCD's L2.
    const int p   = blockIdx.x;
    const int xcd = p & 7;
    const int r_  = p >> 3;            // 0..511
    const int uv  = xcd * 128 + (r_ >> 2);
    const int ot  = r_ & 3;            // o-tile of 128
    const int u = uv >> 5, v = uv & 31;
    const int o0 = ot * 128;
    const int owave = o0 + wave * 16;  // 16 o per wave (n=1)

    // twiddles e^{-2pi i (u p + v q)/32} (sin pre-negated)
    float cs[9], sn[9];
    #pragma unroll
    for (int pp = 0; pp < 3; ++pp) {
        #pragma unroll
        for (int qq = 0; qq < 3; ++qq) {
            int k = (u*pp + v*qq) & 31;
            float a = (float)k * 0.0625f;
            cs[pp*3+qq] = cospif(a);
            sn[pp*3+qq] = -sinpif(a);
        }
    }

    f32x4 accR[4], accI[4];
    #pragma unroll
    for (int m = 0; m < 4; ++m) { accR[m] = (f32x4)(0.0f); accI[m] = (f32x4)(0.0f); }

    // B-construct base: this lane's o row in (t,o,c) taps
    const int o_b = owave + laneO;
    const short* tbase = taps + (size_t)o_b * CC;

    // stage slots (fixed per thread)
    const float* ssrc[2];
    int sidx[2];
    #pragma unroll
    for (int it = 0; it < 2; ++it) {
        int s  = tid + it * 512;           // 0..1023
        int ri = s >> 9;
        int rr = s & 511;
        int b  = rr >> 3;
        int c8 = (rr & 7) * 8;
        ssrc[it] = (ri ? xi : xr) + (size_t)b * HWC + uv * CC + c8;
        sidx[it] = ri * 4096 + b * 64 + (c8 ^ ((b & 7) * 8));
    }

    auto stage_x = [&](short* buf, int kc0) {
        #pragma unroll
        for (int it = 0; it < 2; ++it) {
            float4 f0 = *(const float4*)(ssrc[it] + kc0);
            float4 f1 = *(const float4*)(ssrc[it] + kc0 + 4);
            short8 pk;
            pk[0]=f2bf(f0.x); pk[1]=f2bf(f0.y); pk[2]=f2bf(f0.z); pk[3]=f2bf(f0.w);
            pk[4]=f2bf(f1.x); pk[5]=f2bf(f1.y); pk[6]=f2bf(f1.z); pk[7]=f2bf(f1.w);
            *(short8*)(buf + sidx[it]) = pk;
        }
    };

    // ---- prologue: stage chunk 0 ----
    stage_x(sx, 0);
    __syncthreads();

    #pragma unroll
    for (int ch = 0; ch < 4; ++ch) {
        const int kc0 = ch * 64;
        short* cur = sx + (ch & 1) * 8192;
        short* nxt = sx + ((ch + 1) & 1) * 8192;

        // ---- compute: per ks, build B in regs then MFMA ----
        #pragma unroll
        for (int ks = 0; ks < 2; ++ks) {
            const int cb = kc0 + ks * 32 + laneW * 8;
            short8 bR, bI, bRn;
            {
                float2v ar[4], ai[4];
                #pragma unroll
                for (int j = 0; j < 4; ++j) { ar[j] = (float2v)(0.0f); ai[j] = (float2v)(0.0f); }
                #pragma unroll
                for (int t = 0; t < 9; ++t) {
                    short8 tp = *(const short8*)(tbase + (size_t)t * (OO * CC) + cb);
                    uint4_ tu = __builtin_bit_cast(uint4_, tp);
                    float2v cst = (float2v)(cs[t]);
                    float2v snt = (float2v)(sn[t]);
                    #pragma unroll
                    for (int j = 0; j < 4; ++j) {
                        unsigned uw = tu[j];
                        float2v f;
                        f.x = __uint_as_float(uw << 16);
                        f.y = __uint_as_float(uw & 0xffff0000u);
                        ar[j] = __builtin_elementwise_fma(cst, f, ar[j]);
                        ai[j] = __builtin_elementwise_fma(snt, f, ai[j]);
                    }
                }
                #pragma unroll
                for (int j = 0; j < 4; ++j) {
                    bR[2*j]   = f2bf(ar[j].x);
                    bR[2*j+1] = f2bf(ar[j].y);
                    bI[2*j]   = f2bf(ai[j].x);
                    bI[2*j+1] = f2bf(ai[j].y);
                }
                uint4_ bu = __builtin_bit_cast(uint4_, bR);
                bu ^= 0x80008000u;                 // -wr for imag part
                bRn = __builtin_bit_cast(short8, bu);
            }

            const int cidx = (ks * 32 + laneW * 8) ^ ((laneO & 7) * 8);
            __builtin_amdgcn_s_setprio(1);
            #pragma unroll
            for (int m = 0; m < 4; ++m) {
                int b = m * 16 + laneO;
                short8 a0 = *(const short8*)(cur + b * 64 + cidx);
                short8 a1 = *(const short8*)(cur + 4096 + b * 64 + cidx);
                accR[m] = __builtin_amdgcn_mfma_f32_16x16x32_bf16(a0, bR,  accR[m], 0, 0, 0);
                accR[m] = __builtin_amdgcn_mfma_f32_16x16x32_bf16(a1, bI,  accR[m], 0, 0, 0);
                accI[m] = __builtin_amdgcn_mfma_f32_16x16x32_bf16(a0, bI,  accI[m], 0, 0, 0);
                accI[m] = __builtin_amdgcn_mfma_f32_16x16x32_bf16(a1, bRn, accI[m], 0, 0, 0);
            }
            __builtin_amdgcn_s_setprio(0);
        }

        // ---- stage next chunk into the other buffer; ONE barrier ----
        if (ch < 3) stage_x(nxt, kc0 + 64);
        __syncthreads();
    }

    // ---- epilogue: BN + LeakyReLU, coalesced stores ----
    {
        const int o = owave + laneO;
        float scR = gr[o] * rsqrtf(vr[o] + EPS);
        float mR = mr[o], bR_ = br[o];
        float scI = gi[o] * rsqrtf(vi[o] + EPS);
        float mI = mi_[o], bI_ = bi[o];
        #pragma unroll
        for (int m = 0; m < 4; ++m) {
            #pragma unroll
            for (int e = 0; e < 4; ++e) {
                int b = m * 16 + laneW * 4 + e;
                size_t idx = (size_t)b * HWO + (size_t)uv * OO + o;
                float yr = (accR[m][e] - mR) * scR + bR_;
                outr[idx] = (yr >= 0.f) ? yr : ALPHA * yr;
                float yi = (accI[m][e] - mI) * scI + bI_;
                outi[idx] = (yi >= 0.f) ? yi : ALPHA * yi;
            }
        }
    }
}

extern "C" void kernel_launch(void* const* d_in, const int* in_sizes, int n_in,
                              void* d_out, int out_size, void* d_ws, size_t ws_size,
                              hipStream_t stream) {
    const float* xr = (const float*)d_in[0];
    const float* xi = (const float*)d_in[1];
    const float* w  = (const float*)d_in[2];
    const float* gr = (const float*)d_in[3];
    const float* br = (const float*)d_in[4];
    const float* mr = (const float*)d_in[5];
    const float* vr = (const float*)d_in[6];
    const float* gi = (const float*)d_in[7];
    const float* bi = (const float*)d_in[8];
    const float* mi_ = (const float*)d_in[9];
    const float* vi = (const float*)d_in[10];

    short* taps_t = (short*)d_ws;               // 9*512*256 bf16 = 2.36 MB
    float* outr = (float*)d_out;
    float* outi = outr + (size_t)BB * HWO;

    transpose_taps<<<288, 256, 0, stream>>>(w, taps_t);
    cdot_mfma<<<4096, 512, 0, stream>>>(xr, xi, taps_t,
                                        gr, br, mr, vr,
                                        gi, bi, mi_, vi,
                                        outr, outi);
}

// Round 18
// 258.302 us; speedup vs baseline: 1.7156x; 1.3579x over previous
//
#include <hip/hip_runtime.h>
#include <hip/hip_bf16.h>

#define HH 32
#define WW 32
#define CC 256
#define OO 512
#define BB 64
#define HWC (HH*WW*CC)
#define HWO (HH*WW*OO)
#define EPS 1e-3f
#define ALPHA 0.2f

typedef __attribute__((ext_vector_type(8))) short short8;
typedef __attribute__((ext_vector_type(4))) float f32x4;
typedef __attribute__((ext_vector_type(2))) float float2v;
typedef __attribute__((ext_vector_type(4))) unsigned uint4_;

__device__ __forceinline__ short f2bf(float f) {
    return (short)__builtin_bit_cast(unsigned short, __float2bfloat16(f));
}
__device__ __forceinline__ float sfl(float f) {   // block-uniform -> SGPR
    return __uint_as_float(__builtin_amdgcn_readfirstlane(__float_as_uint(f)));
}

// ---- kernel 0: transpose taps (3,3,C,O) f32 -> (t,O,C) bf16 in ws ----
__global__ __launch_bounds__(256) void transpose_taps(const float* __restrict__ w,
                                                      short* __restrict__ tt) {
    __shared__ float tile[64][65];
    const int bid = blockIdx.x;
    const int t  = bid >> 5;          // 0..8
    const int ct = (bid >> 3) & 3;    // c tile
    const int ob = bid & 7;           // o tile
    const int c0 = ct * 64, o0 = ob * 64;
    const int tid = threadIdx.x;
    const int col = tid & 63;
    const int rq  = tid >> 6;         // 0..3
    #pragma unroll
    for (int r = 0; r < 16; ++r) {
        int c_loc = r * 4 + rq;
        tile[c_loc][col] = w[(size_t)(t * CC + c0 + c_loc) * OO + o0 + col];
    }
    __syncthreads();
    #pragma unroll
    for (int r = 0; r < 16; ++r) {
        int o_loc = r * 4 + rq;
        tt[(size_t)(t * OO + o0 + o_loc) * CC + c0 + col] = f2bf(tile[col][o_loc]);
    }
}

// ---- main fused kernel: 4096 blocks x 512 thr; 128-o tile, n=1 per wave ----
// r10 structure + SGPR twiddles + batched tap loads (1 latency exposure/pass).
__global__ __launch_bounds__(512, 4) void cdot_mfma(
    const float* __restrict__ xr, const float* __restrict__ xi,
    const short* __restrict__ taps,     // (t, o, c) bf16
    const float* __restrict__ gr, const float* __restrict__ br,
    const float* __restrict__ mr, const float* __restrict__ vr,
    const float* __restrict__ gi, const float* __restrict__ bi,
    const float* __restrict__ mi_, const float* __restrict__ vi,
    float* __restrict__ outr, float* __restrict__ outi)
{
    // sx: [2 ri][64 b][64 c] bf16, XOR-swizzled in 8-elt groups. 16 KB.
    // sw: w_freq chunk, R plane [128 o][64 c] + I plane, same swizzle. 32 KB.
    __shared__ short sx[8192];
    __shared__ short sw[16384];

    const int tid  = threadIdx.x;
    const int lane = tid & 63;
    const int wave = tid >> 6;        // 0..7
    const int laneO = lane & 15;
    const int laneW = lane >> 4;

    // uv-major XCD remap (r10 form): 4 same-uv blocks on one XCD's L2.
    const int p   = blockIdx.x;
    const int xcd = p & 7;
    const int r_  = p >> 3;            // 0..511
    const int uv  = xcd * 128 + (r_ >> 2);
    const int ot  = r_ & 3;            // o-tile of 128
    const int u = uv >> 5, v = uv & 31;
    const int o0 = ot * 128;
    const int owave = o0 + wave * 16;  // 16 o per wave (n=1)

    // twiddles e^{-2pi i (u p + v q)/32} (sin pre-negated), hoisted to SGPR
    float cs[9], sn[9];
    #pragma unroll
    for (int pp = 0; pp < 3; ++pp) {
        #pragma unroll
        for (int qq = 0; qq < 3; ++qq) {
            int k = (u*pp + v*qq) & 31;
            float a = (float)k * 0.0625f;
            cs[pp*3+qq] = sfl(cospif(a));
            sn[pp*3+qq] = sfl(-sinpif(a));
        }
    }

    f32x4 accR[4], accI[4];
    #pragma unroll
    for (int m = 0; m < 4; ++m) { accR[m] = (f32x4)(0.0f); accI[m] = (f32x4)(0.0f); }

    // construct assignment: 8 lanes per o-row -> 128 B contiguous tap runs
    const int c8w = (tid & 7) * 8;         // chunk-local c octet base
    const int orw = tid >> 3;              // o-row 0..63 (+64 on pass 1)

    #pragma unroll
    for (int ch = 0; ch < 4; ++ch) {
        const int kc0 = ch * 64;
        __syncthreads();               // previous sweep's reads done; LDS reusable

        short8 tp[9];                  // transient tap batch (36 VGPR in-section)

        // ---- pass 0: issue ALL tap loads first ----
        {
            const short* tb = taps + (size_t)(o0 + orw) * CC + kc0 + c8w;
            #pragma unroll
            for (int t = 0; t < 9; ++t)
                tp[t] = *(const short8*)(tb + (size_t)t * (OO * CC));
        }

        // ---- stage x chunk (issues after taps; cvt drains the whole batch) ----
        #pragma unroll
        for (int it = 0; it < 2; ++it) {
            int s  = tid + it * 512;           // 0..1023
            int ri = s >> 9;
            int rr = s & 511;
            int b  = rr >> 3;
            int c8 = (rr & 7) * 8;
            const float* src = (ri ? xi : xr) + (size_t)b * HWC + uv * CC + kc0 + c8;
            float4 f0 = *(const float4*)src;
            float4 f1 = *(const float4*)(src + 4);
            short8 pk;
            pk[0]=f2bf(f0.x); pk[1]=f2bf(f0.y); pk[2]=f2bf(f0.z); pk[3]=f2bf(f0.w);
            pk[4]=f2bf(f1.x); pk[5]=f2bf(f1.y); pk[6]=f2bf(f1.z); pk[7]=f2bf(f1.w);
            int idx = ri * 4096 + b * 64 + (c8 ^ ((b & 7) * 8));
            *(short8*)(sx + idx) = pk;
        }

        // ---- construct: pass 0 FMA + store, then pass 1 (reuse tp regs) ----
        #pragma unroll
        for (int pass = 0; pass < 2; ++pass) {
            if (pass == 1) {
                const short* tb = taps + (size_t)(o0 + orw + 64) * CC + kc0 + c8w;
                #pragma unroll
                for (int t = 0; t < 9; ++t)
                    tp[t] = *(const short8*)(tb + (size_t)t * (OO * CC));
            }
            float2v ar[4], ai[4];
            #pragma unroll
            for (int j = 0; j < 4; ++j) { ar[j] = (float2v)(0.0f); ai[j] = (float2v)(0.0f); }
            #pragma unroll
            for (int t = 0; t < 9; ++t) {
                uint4_ tu = __builtin_bit_cast(uint4_, tp[t]);
                float2v cst = (float2v)(cs[t]);
                float2v snt = (float2v)(sn[t]);
                #pragma unroll
                for (int j = 0; j < 4; ++j) {
                    unsigned uw = tu[j];
                    float2v f;
                    f.x = __uint_as_float(uw << 16);
                    f.y = __uint_as_float(uw & 0xffff0000u);
                    ar[j] = __builtin_elementwise_fma(cst, f, ar[j]);
                    ai[j] = __builtin_elementwise_fma(snt, f, ai[j]);
                }
            }
            short8 pR, pI;
            #pragma unroll
            for (int j = 0; j < 4; ++j) {
                pR[2*j]   = f2bf(ar[j].x);
                pR[2*j+1] = f2bf(ar[j].y);
                pI[2*j]   = f2bf(ai[j].x);
                pI[2*j+1] = f2bf(ai[j].y);
            }
            const int ol = orw + pass * 64;
            int widx = ol * 64 + (c8w ^ ((ol & 7) * 8));
            *(short8*)(sw + widx)        = pR;
            *(short8*)(sw + 8192 + widx) = pI;
        }
        __syncthreads();

        // ---- MFMA sweep: pure LDS + MFMA (r10 form) ----
        #pragma unroll
        for (int ks = 0; ks < 2; ++ks) {
            const int ol  = wave * 16 + laneO;     // local o 0..127
            const int cpr = (ks * 32 + laneW * 8) ^ ((ol & 7) * 8);
            short8 bR = *(const short8*)(sw + ol * 64 + cpr);
            short8 bI = *(const short8*)(sw + 8192 + ol * 64 + cpr);
            uint4_ bu = __builtin_bit_cast(uint4_, bR);
            bu ^= 0x80008000u;                     // -wr for imag part
            short8 bRn = __builtin_bit_cast(short8, bu);

            const int cidx = (ks * 32 + laneW * 8) ^ ((laneO & 7) * 8);
            __builtin_amdgcn_s_setprio(1);
            #pragma unroll
            for (int m = 0; m < 4; ++m) {
                int b = m * 16 + laneO;
                short8 a0 = *(const short8*)(sx + b * 64 + cidx);
                short8 a1 = *(const short8*)(sx + 4096 + b * 64 + cidx);
                accR[m] = __builtin_amdgcn_mfma_f32_16x16x32_bf16(a0, bR,  accR[m], 0, 0, 0);
                accR[m] = __builtin_amdgcn_mfma_f32_16x16x32_bf16(a1, bI,  accR[m], 0, 0, 0);
                accI[m] = __builtin_amdgcn_mfma_f32_16x16x32_bf16(a0, bI,  accI[m], 0, 0, 0);
                accI[m] = __builtin_amdgcn_mfma_f32_16x16x32_bf16(a1, bRn, accI[m], 0, 0, 0);
            }
            __builtin_amdgcn_s_setprio(0);
        }
    }

    // ---- epilogue: BN + LeakyReLU, coalesced stores ----
    {
        const int o = owave + laneO;
        float scR = gr[o] * rsqrtf(vr[o] + EPS);
        float mR = mr[o], bR_ = br[o];
        float scI = gi[o] * rsqrtf(vi[o] + EPS);
        float mI = mi_[o], bI_ = bi[o];
        #pragma unroll
        for (int m = 0; m < 4; ++m) {
            #pragma unroll
            for (int e = 0; e < 4; ++e) {
                int b = m * 16 + laneW * 4 + e;
                size_t idx = (size_t)b * HWO + (size_t)uv * OO + o;
                float yr = (accR[m][e] - mR) * scR + bR_;
                outr[idx] = (yr >= 0.f) ? yr : ALPHA * yr;
                float yi = (accI[m][e] - mI) * scI + bI_;
                outi[idx] = (yi >= 0.f) ? yi : ALPHA * yi;
            }
        }
    }
}

extern "C" void kernel_launch(void* const* d_in, const int* in_sizes, int n_in,
                              void* d_out, int out_size, void* d_ws, size_t ws_size,
                              hipStream_t stream) {
    const float* xr = (const float*)d_in[0];
    const float* xi = (const float*)d_in[1];
    const float* w  = (const float*)d_in[2];
    const float* gr = (const float*)d_in[3];
    const float* br = (const float*)d_in[4];
    const float* mr = (const float*)d_in[5];
    const float* vr = (const float*)d_in[6];
    const float* gi = (const float*)d_in[7];
    const float* bi = (const float*)d_in[8];
    const float* mi_ = (const float*)d_in[9];
    const float* vi = (const float*)d_in[10];

    short* taps_t = (short*)d_ws;               // 9*512*256 bf16 = 2.36 MB
    float* outr = (float*)d_out;
    float* outi = outr + (size_t)BB * HWO;

    transpose_taps<<<288, 256, 0, stream>>>(w, taps_t);
    cdot_mfma<<<4096, 512, 0, stream>>>(xr, xi, taps_t,
                                        gr, br, mr, vr,
                                        gi, bi, mi_, vi,
                                        outr, outi);
}